// Round 6
// baseline (742.109 us; speedup 1.0000x reference)
//
#include <hip/hip_runtime.h>
#include <hip/hip_bf16.h>

// v7: v5's fused kernel with the inner loop RESTRUCTURED TO FIT 64 VGPRs.
//  Evidence: v4/v5/v6 all show ~400 MB excess WRITE + ~150 MB excess FETCH at
//  VGPR_Count=64 -> allocator targets 64 and spills the linearity loop (live set
//  ~90) to scratch; scratch thrashes L2 -> HBM. v6 proved attribute games don't
//  lift the budget. Fix = reduce the real live set:
//   - ks-outer: only 5 plane frags (20 VGPR) live at a time, not pf[2][5] (40).
//   - vj processed in PAIRS (hf=0,1): ya[2][4] = 8 VGPR accumulators across ks;
//     plane frags re-read per pair (extra ds_read_b128 ~ free vs scratch).
//   - trig: keep only (s1,c1) per vj (8 VGPR); derive c2=2c1^2-1, -s2=-2*s1*c1
//     at the fold site (4 VALU ops per fold block).
//  Live-set estimate: 20 pf + 8 ya + 4 af + 8 z + 8 trig + ~14 addr + 4 stats
//  = ~60 -> fits the 64-VGPR allocation WITHOUT spill.
//  Everything else verbatim from v5 (passed, absmax 0.031): geometry, staging,
//  swizzle, spin barrier (512 blocks all co-resident: LDS 75776 => 2/CU), BN.

typedef __bf16 bf16x8 __attribute__((ext_vector_type(8)));
typedef float f32x4 __attribute__((ext_vector_type(4)));

__device__ __forceinline__ unsigned pack2(float a, float b) {
    __hip_bfloat162 h = __float22bfloat162_rn(make_float2(a, b));
    return *reinterpret_cast<unsigned*>(&h);
}

__global__ __launch_bounds__(512, 4) void conv_bn_fused(
    const float* __restrict__ xr, const float* __restrict__ xi,
    const float* __restrict__ filt, float* __restrict__ out,
    float* __restrict__ gstats, unsigned* __restrict__ done,
    const float* __restrict__ gr, const float* __restrict__ br,
    const float* __restrict__ gi, const float* __restrict__ bi)
{
    __shared__ __align__(16) unsigned short pqT[5 * 4096];     // 40960 B
    __shared__ __align__(16) unsigned short xsh[16 * 16 * 64]; // 32768 B
    __shared__ __align__(16) float statl[512];                 // 2048 B

    const int t = threadIdx.x;
    const int gid = blockIdx.x;
    const int oh = gid >> 8;             // o-half
    const int u  = (gid & 255) >> 1;     // 0..127
    const int vh = gid & 1;              // v-half
    const int obase = oh << 6;
    const int vbase0 = vh << 6;

    unsigned* pq32 = (unsigned*)pqT;
    unsigned* xs32 = (unsigned*)xsh;

    // ---- stage P/Q planes for (u, o-half): once per block
    const float au = 6.28318530717958647692f * (float)u / 128.0f;
    float su1, cu1, su2, cu2;
    __sincosf(au, &su1, &cu1);
    __sincosf(2.0f * au, &su2, &cu2);

    #pragma unroll
    for (int k = 0; k < 4; ++k) {            // 2048 (o, c-pair) items
        int i = t + k * 512;
        int o = i & 63;                       // coalesced filt reads
        int cp = i >> 6;                      // 0..31 (c = 2cp, 2cp+1)
        int g0 = (2 * cp) * 128 + obase + o;
        int g1 = g0 + 128;
        unsigned wd = o * 32 + (((cp >> 2) ^ (o & 7)) << 2) + (cp & 3); // swizzled dword
        #pragma unroll
        for (int b = 0; b < 3; ++b) {
            float f0a = filt[b * 8192 + g0],       f0b = filt[b * 8192 + g1];
            float f1a = filt[(3 + b) * 8192 + g0], f1b = filt[(3 + b) * 8192 + g1];
            float f2a = filt[(6 + b) * 8192 + g0], f2b = filt[(6 + b) * 8192 + g1];
            float Pa = fmaf(cu2, f2a, fmaf(cu1, f1a, f0a));
            float Pb = fmaf(cu2, f2b, fmaf(cu1, f1b, f0b));
            pq32[b * 2048 + wd] = pack2(Pa, Pb);
            if (b > 0) {
                float Qa = fmaf(su2, f2a, su1 * f1a);
                float Qb = fmaf(su2, f2b, su1 * f1b);
                pq32[(b + 2) * 2048 + wd] = pack2(Qa, Qb);
            }
        }
    }

    // ---- wave assignment
    const int wave = t >> 6;
    const int lane = t & 63;
    const int vg   = wave >> 1;       // 4 v's per wave (chunk-local)
    const int nth  = wave & 1;        // o-tile pair: ot = nth*2 + ntl
    const int ln15 = lane & 15;
    const int q    = lane >> 4;
    const int swz  = ln15 & 7;
    const int part = q >> 1;
    const int nbase = (q & 1) * 4;

    const int sv = t >> 5;            // staging: chunk-local v
    const int scp = t & 31;           // staging: c-pair

    float ssum[2] = {0.f, 0.f}, ssq[2] = {0.f, 0.f};

    #pragma unroll 1
    for (int chk = 0; chk < 4; ++chk) {
        // ---- stage x' chunk (v2-verified path)
        {
            const int vglob = vbase0 + chk * 16 + sv;
            #pragma unroll
            for (int n = 0; n < 8; ++n) {
                size_t gi = (((size_t)(n * 128 + u)) * 128 + vglob) * 64 + 2 * scp;
                float2 r  = *(const float2*)(xr + gi);
                float2 m2 = *(const float2*)(xi + gi);
                unsigned rp = pack2(r.x + m2.x, r.y + m2.y);
                unsigned ip = pack2(m2.x - r.x, m2.y - r.y);
                unsigned base = (sv * 16 + n) * 32 + (((scp >> 2) ^ (n & 7)) << 2) + (scp & 3);
                xs32[base] = rp;               // np = n      (r+i)
                xs32[base + 256] = ip;         // np = 8+n    (i-r)
            }
        }
        __syncthreads();

        // ---- per-v trig: ONLY (s1,c1) kept (8 VGPR); harmonics derived at use
        float s1v[4], c1v[4];
        #pragma unroll
        for (int vj = 0; vj < 4; ++vj) {
            float av = 6.28318530717958647692f *
                       (float)(vbase0 + chk * 16 + vg * 4 + vj) / 128.0f;
            __sincosf(av, &s1v[vj], &c1v[vj]);
        }

        // ---- main: ks-outer, vj-pair, immediate fold (fits 64 VGPR)
        #pragma unroll
        for (int ntl = 0; ntl < 2; ++ntl) {
            const int o_loc = (nth * 2 + ntl) * 16 + ln15;
            const unsigned short* prow = &pqT[o_loc * 64];

            #pragma unroll
            for (int hf = 0; hf < 2; ++hf) {
                float ya[2][4] = {{0.f,0.f,0.f,0.f},{0.f,0.f,0.f,0.f}};

                #pragma unroll
                for (int ks = 0; ks < 2; ++ks) {
                    const int foff = (((ks * 4 + q) ^ swz) << 3);
                    bf16x8 pf0 = __builtin_bit_cast(bf16x8, *(const uint4*)(prow + 0 * 4096 + foff));
                    bf16x8 pf1 = __builtin_bit_cast(bf16x8, *(const uint4*)(prow + 1 * 4096 + foff));
                    bf16x8 pf2 = __builtin_bit_cast(bf16x8, *(const uint4*)(prow + 2 * 4096 + foff));
                    bf16x8 pf3 = __builtin_bit_cast(bf16x8, *(const uint4*)(prow + 3 * 4096 + foff));
                    bf16x8 pf4 = __builtin_bit_cast(bf16x8, *(const uint4*)(prow + 4 * 4096 + foff));

                    #pragma unroll
                    for (int j = 0; j < 2; ++j) {
                        const int vj = hf * 2 + j;
                        const unsigned short* xrow =
                            &xsh[((vg * 4 + vj) * 16 + ln15) * 64];
                        bf16x8 af = __builtin_bit_cast(bf16x8,
                            *(const uint4*)(xrow + foff));

                        const float c1 = c1v[vj], s1 = s1v[vj];
                        const float c2  = fmaf(2.0f * c1, c1, -1.0f);  // cos 2v
                        const float ns2 = -2.0f * s1 * c1;             // -sin 2v
                        const f32x4 zz = (f32x4){0.f, 0.f, 0.f, 0.f};

                        f32x4 z;
                        z = __builtin_amdgcn_mfma_f32_16x16x32_bf16(af, pf0, zz, 0, 0, 0);
                        #pragma unroll
                        for (int r = 0; r < 4; ++r) ya[j][r] += z[r];
                        z = __builtin_amdgcn_mfma_f32_16x16x32_bf16(af, pf1, zz, 0, 0, 0);
                        #pragma unroll
                        for (int r = 0; r < 4; ++r) ya[j][r] = fmaf(c1, z[r], ya[j][r]);
                        z = __builtin_amdgcn_mfma_f32_16x16x32_bf16(af, pf2, zz, 0, 0, 0);
                        #pragma unroll
                        for (int r = 0; r < 4; ++r) ya[j][r] = fmaf(c2, z[r], ya[j][r]);
                        z = __builtin_amdgcn_mfma_f32_16x16x32_bf16(af, pf3, zz, 0, 0, 0);
                        #pragma unroll
                        for (int r = 0; r < 4; ++r) ya[j][r] = fmaf(-s1, z[r], ya[j][r]);
                        z = __builtin_amdgcn_mfma_f32_16x16x32_bf16(af, pf4, zz, 0, 0, 0);
                        #pragma unroll
                        for (int r = 0; r < 4; ++r) ya[j][r] = fmaf(ns2, z[r], ya[j][r]);
                    }
                }

                // ---- store + stats for this vj pair
                #pragma unroll
                for (int j = 0; j < 2; ++j) {
                    const int vj = hf * 2 + j;
                    const int vglob = vbase0 + chk * 16 + vg * 4 + vj;
                    size_t base = (size_t)part * 16777216 + (size_t)nbase * 2097152
                                + ((size_t)(u * 128 + vglob)) * 128 + obase + o_loc;
                    #pragma unroll
                    for (int r = 0; r < 4; ++r) {
                        float y = ya[j][r];
                        out[base + (size_t)r * 2097152] = y;   // cached: keep in L3
                        ssum[ntl] += y;
                        ssq[ntl] = fmaf(y, y, ssq[ntl]);
                    }
                }
            }
        }
        __syncthreads();    // xsh fully consumed before next chunk's staging
    }

    // ---- block-level stats reduction -> global atomics (device scope)
    statl[t] = 0.f;
    __syncthreads();
    #pragma unroll
    for (int ntl = 0; ntl < 2; ++ntl) {
        int chn = part * 128 + obase + (nth * 2 + ntl) * 16 + ln15;
        atomicAdd(&statl[chn], ssum[ntl]);
        atomicAdd(&statl[256 + chn], ssq[ntl]);
    }
    __syncthreads();
    atomicAdd(&gstats[t], statl[t]);

    // ================= grid-wide spin barrier (all 512 blocks resident) =========
    __syncthreads();                       // all block's gstats atomics retired
    if (t == 0) {
        __threadfence();
        atomicAdd(done, 1u);
        while (atomicAdd(done, 0u) < 512u) {
            __builtin_amdgcn_s_sleep(2);
        }
        __threadfence();
    }
    __syncthreads();

    // ---- phase 2: all 256 channels' scale/shift into LDS (coherent atomic reads)
    if (t < 256) {
        int pp = t >> 7, o = t & 127;
        const float inv = 1.0f / 131072.0f;
        float s0 = atomicAdd(&gstats[t], 0.0f);
        float s1 = atomicAdd(&gstats[256 + t], 0.0f);
        float mean = s0 * inv;
        float var  = s1 * inv - mean * mean;
        float g = pp ? gi[o] : gr[o];
        float b = pp ? bi[o] : br[o];
        float s = g * rsqrtf(var + 1e-3f);
        statl[t]       = s;
        statl[256 + t] = b - mean * s;
    }
    __syncthreads();

    // ---- phase 3: BN+LeakyReLU on this block's own slice, in place
    const f32x4* scv = (const f32x4*)statl;          // [64] scale vectors
    const f32x4* shv = (const f32x4*)(statl + 256);  // [64] shift vectors
    const int ob4 = obase >> 2;
    #pragma unroll 4
    for (int it2 = 0; it2 < 32; ++it2) {
        int idx = t + it2 * 512;           // 0..16383 over [part][n][v][o/4]
        int oq = idx & 15;
        int vv = (idx >> 4) & 63;
        int nn = (idx >> 10) & 7;
        int pp = idx >> 13;
        size_t e = ((((size_t)(pp * 8 + nn) * 128 + u) * 128
                   + (size_t)(vbase0 + vv)) << 7) + (size_t)(obase + oq * 4);
        f32x4 x = *(const f32x4*)(out + e);
        f32x4 sc = scv[pp * 32 + ob4 + oq];
        f32x4 sh = shv[pp * 32 + ob4 + oq];
        f32x4 y;
        #pragma unroll
        for (int r = 0; r < 4; ++r) {
            float w = fmaf(x[r], sc[r], sh[r]);
            y[r] = w >= 0.0f ? w : 0.2f * w;
        }
        *(f32x4*)(out + e) = y;
    }
}

extern "C" void kernel_launch(void* const* d_in, const int* in_sizes, int n_in,
                              void* d_out, int out_size, void* d_ws, size_t ws_size,
                              hipStream_t stream)
{
    const float* xr   = (const float*)d_in[0];
    const float* xi   = (const float*)d_in[1];
    const float* filt = (const float*)d_in[2];
    const float* gr   = (const float*)d_in[3];
    const float* br   = (const float*)d_in[4];
    const float* gi   = (const float*)d_in[5];
    const float* bi   = (const float*)d_in[6];
    float* out = (float*)d_out;
    float* ws  = (float*)d_ws;

    float* gstats  = ws;                    // 512 floats
    unsigned* done = (unsigned*)(ws + 512); // 1 uint

    (void)hipMemsetAsync(ws, 0, 516 * sizeof(float), stream);
    conv_bn_fused<<<dim3(512), dim3(512), 0, stream>>>(
        xr, xi, filt, out, gstats, done, gr, br, gi, bi);
}

// Round 7
// 366.011 us; speedup vs baseline: 2.0276x; 2.0276x over previous
//
#include <hip/hip_runtime.h>
#include <hip/hip_bf16.h>

// v8: recombination of the two VERIFIED-CLEAN pieces.
//  Evidence after 4 failed rounds: the MFMA-linearity inner loop (v4-v7) is the
//  sole correlate of a 300-900 MB excess-traffic signature (mechanism unproven;
//  v2's higher-live-set synth loop is clean at the same VGPR_Count=64 -> naive
//  spill arithmetic falsified). Abandon linearity.
//  - Conv phase: v2's kernel VERBATIM (F100/W185 clean, 127 us, absmax 0.031).
//    Geometry: block=(u, v-half, o-half), grid 512 = exactly 2 blocks/CU
//    (LDS 75776 B), 4 chunks of 16 v; planes 5x[64o][64c] bf16 XOR-swizzled;
//    per (ntl,ks): unpack 5 plane frags once, synth bf16 kr per vj (4 FMA/val),
//    1 MFMA per (vj,ks) chained into acc[vj].
//  - Fusion: v5's spin barrier + BN phases VERBATIM (passed 3x; adds only the
//    expected ~268 MB). Removes the ~190 us fixed 3-kernel tail.

typedef __bf16 bf16x8 __attribute__((ext_vector_type(8)));
typedef float f32x4 __attribute__((ext_vector_type(4)));

__device__ __forceinline__ unsigned pack2(float a, float b) {
    __hip_bfloat162 h = __float22bfloat162_rn(make_float2(a, b));
    return *reinterpret_cast<unsigned*>(&h);
}
__device__ __forceinline__ void unpack8(uint4 u, float* f) {
    f[0] = __uint_as_float(u.x << 16); f[1] = __uint_as_float(u.x & 0xffff0000u);
    f[2] = __uint_as_float(u.y << 16); f[3] = __uint_as_float(u.y & 0xffff0000u);
    f[4] = __uint_as_float(u.z << 16); f[5] = __uint_as_float(u.z & 0xffff0000u);
    f[6] = __uint_as_float(u.w << 16); f[7] = __uint_as_float(u.w & 0xffff0000u);
}

__global__ __launch_bounds__(512, 4) void conv_bn_fused(
    const float* __restrict__ xr, const float* __restrict__ xi,
    const float* __restrict__ filt, float* __restrict__ out,
    float* __restrict__ gstats, unsigned* __restrict__ done,
    const float* __restrict__ gr, const float* __restrict__ br,
    const float* __restrict__ gi, const float* __restrict__ bi)
{
    __shared__ __align__(16) unsigned short pqT[5 * 4096];     // 40960 B
    __shared__ __align__(16) unsigned short xsh[16 * 16 * 64]; // 32768 B
    __shared__ __align__(16) float statl[512];                 // 2048 B

    const int t = threadIdx.x;
    const int gid = blockIdx.x;
    const int oh = gid >> 8;             // o-half
    const int u  = (gid & 255) >> 1;     // 0..127
    const int vh = gid & 1;              // v-half
    const int obase = oh << 6;
    const int vbase0 = vh << 6;

    unsigned* pq32 = (unsigned*)pqT;
    unsigned* xs32 = (unsigned*)xsh;

    // ---- stage P/Q planes for (u, o-half): once per block
    const float au = 6.28318530717958647692f * (float)u / 128.0f;
    float su1, cu1, su2, cu2;
    __sincosf(au, &su1, &cu1);
    __sincosf(2.0f * au, &su2, &cu2);

    #pragma unroll
    for (int k = 0; k < 4; ++k) {            // 2048 (o, c-pair) items
        int i = t + k * 512;
        int o = i & 63;                       // coalesced filt reads
        int cp = i >> 6;                      // 0..31 (c = 2cp, 2cp+1)
        int g0 = (2 * cp) * 128 + obase + o;
        int g1 = g0 + 128;
        unsigned wd = o * 32 + (((cp >> 2) ^ (o & 7)) << 2) + (cp & 3); // swizzled dword
        #pragma unroll
        for (int b = 0; b < 3; ++b) {
            float f0a = filt[b * 8192 + g0],       f0b = filt[b * 8192 + g1];
            float f1a = filt[(3 + b) * 8192 + g0], f1b = filt[(3 + b) * 8192 + g1];
            float f2a = filt[(6 + b) * 8192 + g0], f2b = filt[(6 + b) * 8192 + g1];
            float Pa = fmaf(cu2, f2a, fmaf(cu1, f1a, f0a));
            float Pb = fmaf(cu2, f2b, fmaf(cu1, f1b, f0b));
            pq32[b * 2048 + wd] = pack2(Pa, Pb);
            if (b > 0) {
                float Qa = fmaf(su2, f2a, su1 * f1a);
                float Qb = fmaf(su2, f2b, su1 * f1b);
                pq32[(b + 2) * 2048 + wd] = pack2(Qa, Qb);
            }
        }
    }

    // ---- wave assignment
    const int wave = t >> 6;
    const int lane = t & 63;
    const int vg   = wave >> 1;       // 4 v's per wave (chunk-local)
    const int nth  = wave & 1;        // o-tile pair: ot = nth*2 + ntl
    const int ln15 = lane & 15;
    const int q    = lane >> 4;
    const int swz  = ln15 & 7;
    const int part = q >> 1;
    const int nbase = (q & 1) * 4;

    const int sv = t >> 5;            // staging: chunk-local v
    const int scp = t & 31;           // staging: c-pair

    float ssum[2] = {0.f, 0.f}, ssq[2] = {0.f, 0.f};

    #pragma unroll 1
    for (int chk = 0; chk < 4; ++chk) {
        // ---- stage x' chunk (v2-verified path)
        {
            const int vglob = vbase0 + chk * 16 + sv;
            #pragma unroll
            for (int n = 0; n < 8; ++n) {
                size_t gi = (((size_t)(n * 128 + u)) * 128 + vglob) * 64 + 2 * scp;
                float2 r  = *(const float2*)(xr + gi);
                float2 m2 = *(const float2*)(xi + gi);
                unsigned rp = pack2(r.x + m2.x, r.y + m2.y);
                unsigned ip = pack2(m2.x - r.x, m2.y - r.y);
                unsigned base = (sv * 16 + n) * 32 + (((scp >> 2) ^ (n & 7)) << 2) + (scp & 3);
                xs32[base] = rp;               // np = n      (r+i)
                xs32[base + 256] = ip;         // np = 8+n    (i-r)
            }
        }
        __syncthreads();

        // ---- per-v trig (v2 verbatim)
        float cv1[4], cv2[4], nsv1[4], nsv2[4];
        #pragma unroll
        for (int vj = 0; vj < 4; ++vj) {
            float av = 6.28318530717958647692f *
                       (float)(vbase0 + chk * 16 + vg * 4 + vj) / 128.0f;
            float s1, c1, s2, c2;
            __sincosf(av, &s1, &c1);
            __sincosf(2.0f * av, &s2, &c2);
            cv1[vj] = c1; cv2[vj] = c2; nsv1[vj] = -s1; nsv2[vj] = -s2;
        }

        // ---- A-fragments (v2 verbatim: swizzled b128, layout == MFMA A order)
        bf16x8 af[4][2];
        #pragma unroll
        for (int vj = 0; vj < 4; ++vj) {
            const unsigned short* xrow = &xsh[((vg * 4 + vj) * 16 + ln15) * 64];
            #pragma unroll
            for (int ks = 0; ks < 2; ++ks) {
                int m = ks * 4 + q;
                af[vj][ks] = __builtin_bit_cast(bf16x8,
                    *(const uint4*)(xrow + ((m ^ swz) << 3)));
            }
        }

        // ---- main loop (v2 verbatim): unpack planes once per ks, synth kr per vj
        #pragma unroll
        for (int ntl = 0; ntl < 2; ++ntl) {
            const int ot = nth * 2 + ntl;
            const int o_loc = ot * 16 + ln15;
            const unsigned short* prow = &pqT[o_loc * 64];
            f32x4 acc[4];
            #pragma unroll
            for (int vj = 0; vj < 4; ++vj) acc[vj] = (f32x4){0.f, 0.f, 0.f, 0.f};

            #pragma unroll
            for (int ks = 0; ks < 2; ++ks) {
                const int m = ks * 4 + q;
                const int foff = (m ^ swz) << 3;     // (o_loc&7)==ln15&7==swz
                float P0[8], P1[8], P2[8], Q1[8], Q2[8];
                unpack8(*(const uint4*)(prow + 0 * 4096 + foff), P0);
                unpack8(*(const uint4*)(prow + 1 * 4096 + foff), P1);
                unpack8(*(const uint4*)(prow + 2 * 4096 + foff), P2);
                unpack8(*(const uint4*)(prow + 3 * 4096 + foff), Q1);
                unpack8(*(const uint4*)(prow + 4 * 4096 + foff), Q2);
                #pragma unroll
                for (int vj = 0; vj < 4; ++vj) {
                    float kr[8];
                    #pragma unroll
                    for (int j = 0; j < 8; ++j) {
                        float tv = fmaf(cv1[vj], P1[j], P0[j]);
                        tv = fmaf(cv2[vj], P2[j], tv);
                        tv = fmaf(nsv1[vj], Q1[j], tv);
                        kr[j] = fmaf(nsv2[vj], Q2[j], tv);
                    }
                    uint4 B;
                    B.x = pack2(kr[0], kr[1]); B.y = pack2(kr[2], kr[3]);
                    B.z = pack2(kr[4], kr[5]); B.w = pack2(kr[6], kr[7]);
                    acc[vj] = __builtin_amdgcn_mfma_f32_16x16x32_bf16(
                        af[vj][ks], __builtin_bit_cast(bf16x8, B), acc[vj], 0, 0, 0);
                }
            }

            // ---- store + stats for this o-tile (cached stores: out fits L3)
            const int o_glob = obase + o_loc;
            #pragma unroll
            for (int vj = 0; vj < 4; ++vj) {
                const int vglob = vbase0 + chk * 16 + vg * 4 + vj;
                size_t base = (size_t)part * 16777216 + (size_t)nbase * 2097152
                            + ((size_t)(u * 128 + vglob)) * 128 + o_glob;
                #pragma unroll
                for (int r = 0; r < 4; ++r) {
                    float y = acc[vj][r];
                    out[base + (size_t)r * 2097152] = y;
                    ssum[ntl] += y;
                    ssq[ntl] = fmaf(y, y, ssq[ntl]);
                }
            }
        }
        __syncthreads();    // xsh fully consumed before next chunk's staging
    }

    // ---- block-level stats reduction -> global atomics (device scope)
    statl[t] = 0.f;
    __syncthreads();
    #pragma unroll
    for (int ntl = 0; ntl < 2; ++ntl) {
        int chn = part * 128 + obase + (nth * 2 + ntl) * 16 + ln15;
        atomicAdd(&statl[chn], ssum[ntl]);
        atomicAdd(&statl[256 + chn], ssq[ntl]);
    }
    __syncthreads();
    atomicAdd(&gstats[t], statl[t]);

    // ================= grid-wide spin barrier (all 512 blocks resident) =========
    __syncthreads();                       // all block's gstats atomics retired
    if (t == 0) {
        __threadfence();
        atomicAdd(done, 1u);
        while (atomicAdd(done, 0u) < 512u) {
            __builtin_amdgcn_s_sleep(2);
        }
        __threadfence();
    }
    __syncthreads();

    // ---- phase 2: all 256 channels' scale/shift into LDS (coherent atomic reads)
    if (t < 256) {
        int pp = t >> 7, o = t & 127;
        const float inv = 1.0f / 131072.0f;
        float s0 = atomicAdd(&gstats[t], 0.0f);
        float s1 = atomicAdd(&gstats[256 + t], 0.0f);
        float mean = s0 * inv;
        float var  = s1 * inv - mean * mean;
        float g = pp ? gi[o] : gr[o];
        float b = pp ? bi[o] : br[o];
        float s = g * rsqrtf(var + 1e-3f);
        statl[t]       = s;
        statl[256 + t] = b - mean * s;
    }
    __syncthreads();

    // ---- phase 3: BN+LeakyReLU on this block's own slice, in place
    const f32x4* scv = (const f32x4*)statl;          // [64] scale vectors
    const f32x4* shv = (const f32x4*)(statl + 256);  // [64] shift vectors
    const int ob4 = obase >> 2;
    #pragma unroll 4
    for (int it2 = 0; it2 < 32; ++it2) {
        int idx = t + it2 * 512;           // 0..16383 over [part][n][v][o/4]
        int oq = idx & 15;
        int vv = (idx >> 4) & 63;
        int nn = (idx >> 10) & 7;
        int pp = idx >> 13;
        size_t e = ((((size_t)(pp * 8 + nn) * 128 + u) * 128
                   + (size_t)(vbase0 + vv)) << 7) + (size_t)(obase + oq * 4);
        f32x4 x = *(const f32x4*)(out + e);
        f32x4 sc = scv[pp * 32 + ob4 + oq];
        f32x4 sh = shv[pp * 32 + ob4 + oq];
        f32x4 y;
        #pragma unroll
        for (int r = 0; r < 4; ++r) {
            float w = fmaf(x[r], sc[r], sh[r]);
            y[r] = w >= 0.0f ? w : 0.2f * w;
        }
        *(f32x4*)(out + e) = y;
    }
}

extern "C" void kernel_launch(void* const* d_in, const int* in_sizes, int n_in,
                              void* d_out, int out_size, void* d_ws, size_t ws_size,
                              hipStream_t stream)
{
    const float* xr   = (const float*)d_in[0];
    const float* xi   = (const float*)d_in[1];
    const float* filt = (const float*)d_in[2];
    const float* gr   = (const float*)d_in[3];
    const float* br   = (const float*)d_in[4];
    const float* gi   = (const float*)d_in[5];
    const float* bi   = (const float*)d_in[6];
    float* out = (float*)d_out;
    float* ws  = (float*)d_ws;

    float* gstats  = ws;                    // 512 floats
    unsigned* done = (unsigned*)(ws + 512); // 1 uint

    (void)hipMemsetAsync(ws, 0, 516 * sizeof(float), stream);
    conv_bn_fused<<<dim3(512), dim3(512), 0, stream>>>(
        xr, xi, filt, out, gstats, done, gr, br, gi, bi);
}